// Round 2
// baseline (1449.003 us; speedup 1.0000x reference)
//
#include <hip/hip_runtime.h>
#include <cstddef>

// ---------------------------------------------------------------------------
// SNN forward, feed-forward pipeline. CORRECTNESS CONTRACT: reproduce R3's
// sequential-in-ascending-j fp32 fmaf chain per (t,b,o) (passed, 1.5e-5).
// R10 FACT: fmaf(+0, w, acc) == acc EXACTLY (acc never -0), so skipping
// zero-spike j's is bit-identical.
//
// R13 (1130us): VALU issue 448us (47%), SALU ~72% busy on CU-shared unit.
// R14 (1327us, FAILED): float-ternary gate sank to VALU (v_cndmask): VALU
// issue 448->670us (+50%) — exactly 2 VALU x 32t x act-j. Lesson: gate must
// be INTEGER arithmetic on an SGPR value to stay scalar.
// R15: cut SALU 3x instead of moving it:
//   1) wave = (b, t-HALF): 16 t x full O per wave, NAO=O/64 (8 for O=512).
//      acc = 16xNAO = 128 regs. Per-b gate SALU halves (scales as 512/NAO).
//      Epilogue chain t0..31 stitched across the wave pair via LDS handoff
//      (v, cur, zw + one barrier) — identical fp32 chain.
//   2) gate av = ((wh>>t)&1)*scale_i -> s_bfe_u32 + s_mul_i32 (2 independent
//      SALU, no SCC chain; R13 was 3 chained).
//   3) half-word emptiness test (w>>16*th)&0xFFFF — extra skips for free.
//   4) keep: mask windows (1 coalesced load / 64 j, readlane consume),
//      4-buffer depth-2 unconditional W prefetch (2-j groups).
// Cost accepted: full row per t-half wave => 2x L1 read traffic (~256 cyc/j/CU
// at 64B/cyc vs ~205 cyc/j VALU floor) — candidate next ceiling.
// acc static-indexed (R4/R5/R7); ~210 unified regs -> 2 waves/SIMD.
// ---------------------------------------------------------------------------

#define THREADS 256

// WT offsets (floats): WT1[2048][512], WT2[512][512], WT3[512][256],
// WT4[256][128] (w4 zero-padded 100->128 cols)
#define WOFF1 0
#define WOFF2 1048576
#define WOFF3 1310720
#define WOFF4 1441792
#define WTOT  1474560

__global__ __launch_bounds__(THREADS) void prep_kernel(
    const float* __restrict__ w1, const float* __restrict__ w2,
    const float* __restrict__ w3, const float* __restrict__ w4,
    float* __restrict__ wt)
{
  int idx = blockIdx.x * THREADS + threadIdx.x;
  if (idx >= WTOT) return;
  if (idx < WOFF2) {
    int j = idx >> 9, o = idx & 511;
    wt[idx] = w1[o * 2048 + j];
  } else if (idx < WOFF3) {
    int r = idx - WOFF2, j = r >> 9, o = r & 511;
    wt[idx] = w2[o * 512 + j];
  } else if (idx < WOFF4) {
    int r = idx - WOFF3, j = r >> 8, o = r & 255;
    wt[idx] = w3[o * 512 + j];
  } else {
    int r = idx - WOFF4, j = r >> 7, o = r & 127;
    wt[idx] = (o < 100) ? w4[o * 256 + j] : 0.0f;
  }
}

// Encoder (verbatim R3 arithmetic); writes em[b][j] word = bits over t.
__global__ __launch_bounds__(THREADS) void enc_kernel(
    const float* __restrict__ x, const float* __restrict__ fscale,
    unsigned* __restrict__ em, int b0)
{
  int idx = blockIdx.x * THREADS + threadIdx.x;
  int b = idx >> 11, j = idx & 2047;
  float c = 2.0f * fscale[0] * x[((size_t)(b0 + b) << 11) + j];
  float v = 0.0f;
  unsigned m = 0u;
#pragma unroll
  for (int t = 0; t < 32; ++t) {
    v = v + 0.1f * (c - v);
    unsigned z = ((v - 0.33f) > 0.0f) ? 1u : 0u;
    m |= z << t;
    if (z) v = 0.0f;
  }
  em[idx] = m;
}

// ---------------------------------------------------------------------------
// Sparse-j fused GEMM(+LIF / +LI readout), t-half-split waves.
//   mIn: em-format masks [b][J], word = bits over t (wave-uniform per j)
//   WT:  [j][o] pre-transposed weights (rows L2-resident)
// Block: 4 waves = 2 b x 2 t-halves. Wave covers ALL O (lane owns NAO=O/64
// consecutive o's) for its 16 t's; acc[16][NAO]. Masks: one word-per-lane
// window load per 64 j, consumed via v_readlane; gate = s_bfe+s_mul (SALU).
// W rows: unconditional depth-2 prefetch, 4 rotating buffers, 2-j groups.
// Epilogue: t0..15 wave computes LIF/LI states, hands (v,cur,zw) to t16..31
// wave via LDS + one barrier; chain is bit-identical to the 32-t original.
// ---------------------------------------------------------------------------
template <int O, bool FINAL>
__global__ __launch_bounds__(THREADS, 2) void gemm_sparse(
    const unsigned* __restrict__ mIn, const float* __restrict__ WT,
    int J, const float* __restrict__ es,
    unsigned* __restrict__ mOut, float* __restrict__ out, int bbase)
{
  constexpr int NAO = O / 64;                // o's per lane (full O per wave)
  typedef float fv __attribute__((ext_vector_type(NAO)));
  const int tid = threadIdx.x;
  const int lane = tid & 63, wvid = tid >> 6;
  const int bl = wvid >> 1;                  // b within block (2 b / block)
  const int th = wvid & 1;                   // t-half: 0 -> t0..15, 1 -> t16..31
  const int b = blockIdx.x * 2 + bl;
  const int ob = lane * NAO;
  const float* const wbase = WT + ob;        // row j at wbase + j*O
  const unsigned tsh = (unsigned)(th << 4);  // uniform per wave
  float scalef = es ? 5.0f * es[0] : 1.0f;   // same expr as R3
  const int scale_i =
      __builtin_amdgcn_readfirstlane(__float_as_int(scalef));

  __shared__ float    ls_v[2][O];            // t-half state handoff
  __shared__ float    ls_c[2][O];
  __shared__ unsigned ls_z[2][O];

  float acc[16][NAO];
#pragma unroll
  for (int t = 0; t < 16; ++t)
#pragma unroll
    for (int k = 0; k < NAO; ++k) acc[t][k] = 0.0f;

  const unsigned* mrow = mIn + (size_t)b * J;
  const int NW = J >> 6;                     // 64-j mask windows (32/8/8/4)

  auto wload = [&](int g, fv* wv) {          // UNCONDITIONAL: no branches,
#pragma unroll                               // no mask dependency. group = 2 j
    for (int r = 0; r < 2; ++r)
      wv[r] = *(const fv*)(wbase + (size_t)(g * 2 + r) * O);
  };
  auto fg = [&](unsigned mw, int q2, const fv* wv) {
#pragma unroll
    for (int jj = 0; jj < 2; ++jj) {
      unsigned w = (unsigned)__builtin_amdgcn_readlane((int)mw, q2 * 2 + jj);
      unsigned wh = (w >> tsh) & 0xFFFFu;    // this wave's 16 t-bits
      if (wh) {                              // wave-uniform scalar branch
#pragma unroll
        for (int t = 0; t < 16; ++t) {
          // av = bit ? scale : 0 — INTEGER SGPR math: s_bfe_u32 + s_mul_i32
          float av = __int_as_float((int)((wh >> t) & 1u) * scale_i);
#pragma unroll
          for (int k = 0; k < NAO; ++k)
            acc[t][k] = fmaf(av, wv[jj][k], acc[t][k]);
        }
      }
    }
  };

  // depth-2 W pipeline over 4 buffers (2-j groups); masks one window ahead.
  fv wvA[2], wvB[2], wvC[2], wvD[2];
  unsigned mwC = mrow[lane];                 // window 0: word per lane
  wload(0, wvA);
  wload(1, wvB);
#pragma unroll 1
  for (int w = 0; w < NW; ++w) {
    // prefetch next mask window (last window: benign same-row reload)
    unsigned mwN = mrow[((w + 1 < NW) ? (w + 1) << 6 : w << 6) + lane];
    const int gb = w << 5;                   // 32 groups of 2 j per window
#pragma unroll 1
    for (int q = 0; q < 32; q += 4) {
      const int g = gb + q;
      wload(g + 2, wvC);                     // lands 2 groups before use
      fg(mwC, q + 0, wvA);
      wload(g + 3, wvD);
      fg(mwC, q + 1, wvB);
      wload(g + 4, wvA);                     // next iter's first buffer
      fg(mwC, q + 2, wvC);
      wload(g + 5, wvB);                     // (tail overrun <=12 rows: lands
      fg(mwC, q + 3, wvD);                   //  in next WT block / em ws: safe)
    }
    mwC = mwN;
  }

  // ---- epilogue: t-half handoff through LDS, chain bit-identical to R3 ----
  if (th == 0) {                             // t = 0..15
#pragma unroll
    for (int k = 0; k < NAO; ++k) {
      float v = 0.0f, cur = 0.0f;
      unsigned zw = 0u;
#pragma unroll
      for (int t2 = 0; t2 < 16; ++t2) {      // verbatim R3 lif_int / out_li
        v = v + 0.1f * (cur - v);
        if (!FINAL) {
          unsigned z = ((v - 0.33f) > 0.0f) ? 1u : 0u;
          zw |= z << t2;
          if (z) v = 0.0f;
        }
        cur = 0.8f * cur + acc[t2][k];
      }
      ls_v[bl][ob + k] = v;
      ls_c[bl][ob + k] = cur;
      if (!FINAL) ls_z[bl][ob + k] = zw;
    }
  }
  __syncthreads();
  if (th == 1) {                             // t = 16..31, continue the chain
#pragma unroll
    for (int k = 0; k < NAO; ++k) {
      float v = ls_v[bl][ob + k], cur = ls_c[bl][ob + k];
      unsigned zw = FINAL ? 0u : ls_z[bl][ob + k];
#pragma unroll
      for (int t2 = 0; t2 < 16; ++t2) {
        v = v + 0.1f * (cur - v);
        if (!FINAL) {
          unsigned z = ((v - 0.33f) > 0.0f) ? 1u : 0u;
          zw |= z << (16 + t2);
          if (z) v = 0.0f;
        }
        cur = 0.8f * cur + acc[t2][k];
      }
      if (FINAL) {
        int o = ob + k;
        if (o < 100) out[(size_t)(bbase + b) * 100 + o] = v;
      } else {
        mOut[(size_t)b * O + ob + k] = zw;   // em-format for next layer
      }
    }
  }
}

extern "C" void kernel_launch(void* const* d_in, const int* in_sizes, int n_in,
                              void* d_out, int out_size, void* d_ws, size_t ws_size,
                              hipStream_t stream)
{
  const float* x  = (const float*)d_in[0];
  const float* w1 = (const float*)d_in[1];
  const float* w2 = (const float*)d_in[2];
  const float* w3 = (const float*)d_in[3];
  const float* w4 = (const float*)d_in[4];
  const float* fs = (const float*)d_in[5];
  const float* es = (const float*)d_in[6];
  float* out = (float*)d_out;
  (void)in_sizes; (void)n_in; (void)out_size;

  // ws: WT (5.9 MB) + em + s1m + s2m + s3m (all em-format words)
  int Bc = 2048;
  auto need = [](int bc) -> size_t {
    return ((size_t)WTOT + (size_t)bc * (2048 + 512 + 512 + 256)) * 4;
  };
  while (Bc > 64 && need(Bc) > ws_size) Bc >>= 1;

  float* WT = (float*)d_ws;
  unsigned* em  = (unsigned*)(WT + WTOT);
  unsigned* s1m = em  + (size_t)Bc * 2048;
  unsigned* s2m = s1m + (size_t)Bc * 512;
  unsigned* s3m = s2m + (size_t)Bc * 512;

  prep_kernel<<<(WTOT + THREADS - 1) / THREADS, THREADS, 0, stream>>>(
      w1, w2, w3, w4, WT);

  for (int b0 = 0; b0 < 2048; b0 += Bc) {
    enc_kernel<<<(Bc * 2048) / THREADS, THREADS, 0, stream>>>(x, fs, em, b0);
    // L1: J=2048 -> O=512, scale = 5*encoder_scalar
    gemm_sparse<512, false><<<Bc / 2, THREADS, 0, stream>>>(
        em, WT + WOFF1, 2048, es, s1m, nullptr, 0);
    // L2: J=512 -> O=512
    gemm_sparse<512, false><<<Bc / 2, THREADS, 0, stream>>>(
        s1m, WT + WOFF2, 512, nullptr, s2m, nullptr, 0);
    // L3: J=512 -> O=256
    gemm_sparse<256, false><<<Bc / 2, THREADS, 0, stream>>>(
        s2m, WT + WOFF3, 512, nullptr, s3m, nullptr, 0);
    // L4 (readout): J=256 -> O=128 (padded), LI epilogue -> out
    gemm_sparse<128, true><<<Bc / 2, THREADS, 0, stream>>>(
        s3m, WT + WOFF4, 256, nullptr, nullptr, out, b0);
  }
}